// Round 1
// baseline (364.274 us; speedup 1.0000x reference)
//
#include <hip/hip_runtime.h>

// Problem constants (B=2, H=8, N=2048, D=64, fp32 in, fp32 out)
#define N_SEQ 2048
#define D_DIM 64
#define BH_CNT 16
#define TILE 128
#define LDSTR 72  // 64 + 8 bf16 pad -> 144B row stride; uniform bank load for b128 reads

typedef __attribute__((ext_vector_type(8))) short bf16x8;
typedef __attribute__((ext_vector_type(4))) float f32x4;

__device__ __forceinline__ short f2bf(float f) {
  // RNE float -> bf16 (inputs are finite/normal; no NaN handling needed)
  union { float f; unsigned u; } v; v.f = f;
  unsigned r = v.u + 0x7FFFu + ((v.u >> 16) & 1u);
  return (short)(r >> 16);
}

__device__ __forceinline__ float hyp_dist(float qns, float kns, float qk) {
  // Matches reference: diff clamp 0, denom clamp 1e-6, arccosh via log form.
  // t2 = cosh_arg - 1 >= 0 always, so the max(cosh_arg,1) clamp is implicit.
  float diff  = fmaxf(qns + kns - 2.0f * qk, 0.0f);
  float denom = fmaxf((1.0f - qns) * (1.0f - kns), 1e-6f);
  float t2 = __fdividef(2.0f * diff, denom);
  float s  = __builtin_amdgcn_sqrtf(t2 * (t2 + 2.0f));
  return __logf(1.0f + t2 + s);  // arccosh(1+t2), stable for all t2>=0
}

__global__ void hyp_kernel(const float* __restrict__ qg,
                           const float* __restrict__ kg,
                           float* __restrict__ out)
{
  __shared__ short Qs[TILE * LDSTR];
  __shared__ short Ks[TILE * LDSTR];
  __shared__ float qn_s[TILE];
  __shared__ float kn_s[TILE];

  const int t  = threadIdx.x;
  const int bh = blockIdx.z;
  const int ti = blockIdx.y;  // Q row tile
  const int tj = blockIdx.x;  // K row tile

  // ---- stage Q/K tiles (fp32 -> bf16) with fused fp32 row norms ----
  // Tile is 128 rows x 64 dims, contiguous 32KB in global (full D per row).
  const float* gq = qg + ((size_t)bh * N_SEQ + (size_t)ti * TILE) * D_DIM;
  const float* gk = kg + ((size_t)bh * N_SEQ + (size_t)tj * TILE) * D_DIM;
#pragma unroll
  for (int m = 0; m < 2; ++m) {
    const float* g = m ? gk : gq;
    short* lds     = m ? Ks : Qs;
    float* nrm     = m ? kn_s : qn_s;
#pragma unroll
    for (int it = 0; it < 4; ++it) {
      int f8  = it * 256 + t;      // 8-float chunk index, 0..1023
      int row = f8 >> 3;           // 8 chunks per row
      int cd  = (f8 & 7) * 8;      // dim offset
      const float4* gp = (const float4*)(g + (size_t)f8 * 8);
      float4 v0 = gp[0];
      float4 v1 = gp[1];
      // fp32 partial norm (8 lanes t=8r..8r+7 own one row)
      float p = v0.x*v0.x + v0.y*v0.y + v0.z*v0.z + v0.w*v0.w
              + v1.x*v1.x + v1.y*v1.y + v1.z*v1.z + v1.w*v1.w;
      p += __shfl_xor(p, 1);
      p += __shfl_xor(p, 2);
      p += __shfl_xor(p, 4);
      if ((t & 7) == 0) nrm[row] = p;
      bf16x8 pk;
      pk[0]=f2bf(v0.x); pk[1]=f2bf(v0.y); pk[2]=f2bf(v0.z); pk[3]=f2bf(v0.w);
      pk[4]=f2bf(v1.x); pk[5]=f2bf(v1.y); pk[6]=f2bf(v1.z); pk[7]=f2bf(v1.w);
      *(bf16x8*)&lds[row * LDSTR + cd] = pk;  // 16B-aligned ds_write_b128
    }
  }
  __syncthreads();

  // ---- MFMA: compute D[j][i] = sum_d K[j][d]*Q[i][d] (transposed so the
  //      C/D reg axis (row=quad*4+reg) is the fast output dim j -> float4 stores)
  const int lane = t & 63;
  const int wv   = t >> 6;          // 4 waves, 2x2 over the 128x128 tile
  const int wj   = (wv & 1) * 64;   // j sub-block (MFMA m axis)
  const int wi   = (wv >> 1) * 64;  // i sub-block (MFMA n axis)
  const int l15  = lane & 15;
  const int quad = lane >> 4;

  const f32x4 zero = {0.0f, 0.0f, 0.0f, 0.0f};
  f32x4 acc[4][4];
#pragma unroll
  for (int a = 0; a < 4; ++a)
#pragma unroll
    for (int b = 0; b < 4; ++b)
      acc[a][b] = zero;

#pragma unroll
  for (int s = 0; s < 2; ++s) {       // K = 64 = 2 x 32
    const int koff = s * 32 + quad * 8;
    bf16x8 fa[4], fb[4];
#pragma unroll
    for (int mj = 0; mj < 4; ++mj)    // A operand: K rows (j)
      fa[mj] = *(const bf16x8*)&Ks[(wj + mj * 16 + l15) * LDSTR + koff];
#pragma unroll
    for (int ni = 0; ni < 4; ++ni)    // B operand: Q rows (i)
      fb[ni] = *(const bf16x8*)&Qs[(wi + ni * 16 + l15) * LDSTR + koff];
#pragma unroll
    for (int mj = 0; mj < 4; ++mj)
#pragma unroll
      for (int ni = 0; ni < 4; ++ni)
        acc[mj][ni] = __builtin_amdgcn_mfma_f32_16x16x32_bf16(
            fa[mj], fb[ni], acc[mj][ni], 0, 0, 0);
  }

  // ---- epilogue: hyperbolic distance + float4 stores ----
  float* outb = out + (size_t)bh * N_SEQ * N_SEQ;
#pragma unroll
  for (int mj = 0; mj < 4; ++mj) {
    const int jl = wj + mj * 16 + quad * 4;           // local j base (4 consecutive)
    const float4 kn4 = *(const float4*)&kn_s[jl];
    const int gj = tj * TILE + jl;
#pragma unroll
    for (int ni = 0; ni < 4; ++ni) {
      const int il = wi + ni * 16 + l15;              // local i
      const float qns = qn_s[il];
      const int gi = ti * TILE + il;
      f32x4 a4 = acc[mj][ni];
      float4 res;
      res.x = hyp_dist(qns, kn4.x, a4[0]);
      res.y = hyp_dist(qns, kn4.y, a4[1]);
      res.z = hyp_dist(qns, kn4.z, a4[2]);
      res.w = hyp_dist(qns, kn4.w, a4[3]);
      *(float4*)(outb + (size_t)gi * N_SEQ + gj) = res;
    }
  }
}

extern "C" void kernel_launch(void* const* d_in, const int* in_sizes, int n_in,
                              void* d_out, int out_size, void* d_ws, size_t ws_size,
                              hipStream_t stream) {
  const float* q = (const float*)d_in[0];
  const float* k = (const float*)d_in[1];
  float* out = (float*)d_out;
  dim3 grid(N_SEQ / TILE, N_SEQ / TILE, BH_CNT);  // (16,16,16) = 4096 blocks
  hyp_kernel<<<grid, 256, 0, stream>>>(q, k, out);
}

// Round 2
// 321.156 us; speedup vs baseline: 1.1343x; 1.1343x over previous
//
#include <hip/hip_runtime.h>

// Problem constants (B=2, H=8, N=2048, D=64, fp32 in, fp32 out)
#define N_SEQ 2048
#define D_DIM 64
#define BH_CNT 16
#define TILE 64     // 64x64 output tile per block: low reg pressure, high occupancy
#define LDSTR 72    // 64 + 8 bf16 pad

typedef __attribute__((ext_vector_type(8))) short bf16x8;
typedef __attribute__((ext_vector_type(4))) float f32x4;

__device__ __forceinline__ short f2bf(float f) {
  union { float f; unsigned u; } v; v.f = f;
  unsigned r = v.u + 0x7FFFu + ((v.u >> 16) & 1u);
  return (short)(r >> 16);
}

__device__ __forceinline__ float hyp_dist(float qns, float kns, float qk) {
  float diff  = fmaxf(qns + kns - 2.0f * qk, 0.0f);
  float denom = fmaxf((1.0f - qns) * (1.0f - kns), 1e-6f);
  float t2 = __fdividef(2.0f * diff, denom);
  float s  = __builtin_amdgcn_sqrtf(t2 * (t2 + 2.0f));
  return __logf(1.0f + t2 + s);  // arccosh(1+t2)
}

__global__ void hyp_kernel(const float* __restrict__ qg,
                           const float* __restrict__ kg,
                           float* __restrict__ out)
{
  __shared__ short Qs[TILE * LDSTR];   // 9216 B
  __shared__ short Ks[TILE * LDSTR];   // 9216 B
  __shared__ float qn_s[TILE];
  __shared__ float kn_s[TILE];

  const int t  = threadIdx.x;
  const int bh = blockIdx.z;
  const int ti = blockIdx.y;  // Q row tile (i)
  const int tj = blockIdx.x;  // K row tile (j)

  // ---- stage Q/K 64x64 tiles (fp32 -> bf16), fused fp32 row norms ----
  // Each thread: one quarter-row (16 floats). 4 threads per row.
  const int row  = t >> 2;        // 0..63
  const int part = t & 3;         // 0..3
  const float* gq = qg + ((size_t)bh * N_SEQ + (size_t)ti * TILE) * D_DIM;
  const float* gk = kg + ((size_t)bh * N_SEQ + (size_t)tj * TILE) * D_DIM;
#pragma unroll
  for (int m = 0; m < 2; ++m) {
    const float* g = (m ? gk : gq) + row * D_DIM + part * 16;
    short* lds     = (m ? Ks : Qs) + row * LDSTR + part * 16;
    float* nrm     = m ? kn_s : qn_s;
    float4 v0 = ((const float4*)g)[0];
    float4 v1 = ((const float4*)g)[1];
    float4 v2 = ((const float4*)g)[2];
    float4 v3 = ((const float4*)g)[3];
    float p = v0.x*v0.x + v0.y*v0.y + v0.z*v0.z + v0.w*v0.w
            + v1.x*v1.x + v1.y*v1.y + v1.z*v1.z + v1.w*v1.w
            + v2.x*v2.x + v2.y*v2.y + v2.z*v2.z + v2.w*v2.w
            + v3.x*v3.x + v3.y*v3.y + v3.z*v3.z + v3.w*v3.w;
    p += __shfl_xor(p, 1);
    p += __shfl_xor(p, 2);
    if (part == 0) nrm[row] = p;
    bf16x8 pk0, pk1;
    pk0[0]=f2bf(v0.x); pk0[1]=f2bf(v0.y); pk0[2]=f2bf(v0.z); pk0[3]=f2bf(v0.w);
    pk0[4]=f2bf(v1.x); pk0[5]=f2bf(v1.y); pk0[6]=f2bf(v1.z); pk0[7]=f2bf(v1.w);
    pk1[0]=f2bf(v2.x); pk1[1]=f2bf(v2.y); pk1[2]=f2bf(v2.z); pk1[3]=f2bf(v2.w);
    pk1[4]=f2bf(v3.x); pk1[5]=f2bf(v3.y); pk1[6]=f2bf(v3.z); pk1[7]=f2bf(v3.w);
    ((bf16x8*)lds)[0] = pk0;
    ((bf16x8*)lds)[1] = pk1;
  }
  __syncthreads();

  // ---- MFMA: transposed product D[j][i] = sum_d K[j][d]*Q[i][d]
  //      so the C/D reg axis (row=quad*4+reg) is the fast output dim j.
  const int lane = t & 63;
  const int wv   = t >> 6;          // 4 waves, 2x2 over the 64x64 tile
  const int wj   = (wv & 1) * 32;   // j sub-block (MFMA m axis)
  const int wi   = (wv >> 1) * 32;  // i sub-block (MFMA n axis)
  const int l15  = lane & 15;
  const int quad = lane >> 4;

  const f32x4 zero = {0.0f, 0.0f, 0.0f, 0.0f};
  f32x4 acc[2][2];
#pragma unroll
  for (int a = 0; a < 2; ++a)
#pragma unroll
    for (int b = 0; b < 2; ++b)
      acc[a][b] = zero;

#pragma unroll
  for (int s = 0; s < 2; ++s) {       // K = 64 = 2 x 32
    const int koff = s * 32 + quad * 8;
    bf16x8 fa[2], fb[2];
#pragma unroll
    for (int mj = 0; mj < 2; ++mj)    // A operand: K rows (j)
      fa[mj] = *(const bf16x8*)&Ks[(wj + mj * 16 + l15) * LDSTR + koff];
#pragma unroll
    for (int ni = 0; ni < 2; ++ni)    // B operand: Q rows (i)
      fb[ni] = *(const bf16x8*)&Qs[(wi + ni * 16 + l15) * LDSTR + koff];
#pragma unroll
    for (int mj = 0; mj < 2; ++mj)
#pragma unroll
      for (int ni = 0; ni < 2; ++ni)
        acc[mj][ni] = __builtin_amdgcn_mfma_f32_16x16x32_bf16(
            fa[mj], fb[ni], acc[mj][ni], 0, 0, 0);
  }

  // ---- epilogue: hyperbolic distance + float4 stores ----
  float* outb = out + (size_t)bh * N_SEQ * N_SEQ;
#pragma unroll
  for (int mj = 0; mj < 2; ++mj) {
    const int jl = wj + mj * 16 + quad * 4;     // 4 consecutive j per lane
    const float4 kn4 = *(const float4*)&kn_s[jl];
    const int gj = tj * TILE + jl;
#pragma unroll
    for (int ni = 0; ni < 2; ++ni) {
      const int il = wi + ni * 16 + l15;
      const float qns = qn_s[il];
      const int gi = ti * TILE + il;
      f32x4 a4 = acc[mj][ni];
      float4 res;
      res.x = hyp_dist(qns, kn4.x, a4[0]);
      res.y = hyp_dist(qns, kn4.y, a4[1]);
      res.z = hyp_dist(qns, kn4.z, a4[2]);
      res.w = hyp_dist(qns, kn4.w, a4[3]);
      *(float4*)(outb + (size_t)gi * N_SEQ + gj) = res;
    }
  }
}

extern "C" void kernel_launch(void* const* d_in, const int* in_sizes, int n_in,
                              void* d_out, int out_size, void* d_ws, size_t ws_size,
                              hipStream_t stream) {
  const float* q = (const float*)d_in[0];
  const float* k = (const float*)d_in[1];
  float* out = (float*)d_out;
  dim3 grid(N_SEQ / TILE, N_SEQ / TILE, BH_CNT);  // (32,32,16) = 16384 blocks
  hyp_kernel<<<grid, 256, 0, stream>>>(q, k, out);
}